// Round 8
// baseline (15327.943 us; speedup 1.0000x reference)
//
#include <hip/hip_runtime.h>

#define SEQ 8192
#define H 1024

// ---------------------------------------------------------------------------
// Projection GEMM (NT): C[i][j] = bias[j] + sum_k A[i][k]*B[j][k]
// (unchanged — ~0.6 ms, not the bottleneck)
// ---------------------------------------------------------------------------
#define KC 32
#define LDT 68

__global__ __launch_bounds__(256) void proj_gemm(
    const float* __restrict__ A,
    const float* __restrict__ B0, const float* __restrict__ b0, float* __restrict__ C0,
    const float* __restrict__ B1, const float* __restrict__ b1, float* __restrict__ C1,
    const float* __restrict__ B2, const float* __restrict__ b2, float* __restrict__ C2)
{
    __shared__ __align__(16) float As[KC * LDT];
    __shared__ __align__(16) float Bs[KC * LDT];

    const float* Bm; const float* bias; float* C;
    if (blockIdx.z == 0)      { Bm = B0; bias = b0; C = C0; }
    else if (blockIdx.z == 1) { Bm = B1; bias = b1; C = C1; }
    else                      { Bm = B2; bias = b2; C = C2; }

    const int j0 = blockIdx.x * 64;
    const int i0 = blockIdx.y * 64;
    const int tid = threadIdx.x;
    const int tx = tid & 15, ty = tid >> 4;
    const int lrow = tid >> 3;
    const int lkq  = tid & 7;

    float acc[4][4];
#pragma unroll
    for (int r = 0; r < 4; r++)
#pragma unroll
        for (int c = 0; c < 4; c++) acc[r][c] = 0.f;

    for (int k0 = 0; k0 < H; k0 += KC) {
#pragma unroll
        for (int half = 0; half < 2; half++) {
            const int row = lrow + half * 32;
            float4 a = *(const float4*)&A[(size_t)(i0 + row) * H + k0 + 4 * lkq];
            As[(4 * lkq + 0) * LDT + row] = a.x;
            As[(4 * lkq + 1) * LDT + row] = a.y;
            As[(4 * lkq + 2) * LDT + row] = a.z;
            As[(4 * lkq + 3) * LDT + row] = a.w;
            float4 b = *(const float4*)&Bm[(size_t)(j0 + row) * H + k0 + 4 * lkq];
            Bs[(4 * lkq + 0) * LDT + row] = b.x;
            Bs[(4 * lkq + 1) * LDT + row] = b.y;
            Bs[(4 * lkq + 2) * LDT + row] = b.z;
            Bs[(4 * lkq + 3) * LDT + row] = b.w;
        }
        __syncthreads();
#pragma unroll
        for (int k = 0; k < KC; k++) {
            float4 a4 = *(const float4*)&As[k * LDT + ty * 4];
            float4 b4 = *(const float4*)&Bs[k * LDT + tx * 4];
            acc[0][0] += a4.x * b4.x; acc[0][1] += a4.x * b4.y;
            acc[0][2] += a4.x * b4.z; acc[0][3] += a4.x * b4.w;
            acc[1][0] += a4.y * b4.x; acc[1][1] += a4.y * b4.y;
            acc[1][2] += a4.y * b4.z; acc[1][3] += a4.y * b4.w;
            acc[2][0] += a4.z * b4.x; acc[2][1] += a4.z * b4.y;
            acc[2][2] += a4.z * b4.z; acc[2][3] += a4.z * b4.w;
            acc[3][0] += a4.w * b4.x; acc[3][1] += a4.w * b4.y;
            acc[3][2] += a4.w * b4.z; acc[3][3] += a4.w * b4.w;
        }
        __syncthreads();
    }

    float4 bi = *(const float4*)&bias[j0 + tx * 4];
#pragma unroll
    for (int r = 0; r < 4; r++) {
        float4 o;
        o.x = acc[r][0] + bi.x; o.y = acc[r][1] + bi.y;
        o.z = acc[r][2] + bi.z; o.w = acc[r][3] + bi.w;
        *(float4*)&C[(size_t)(i0 + ty * 4 + r) * H + j0 + tx * 4] = o;
    }
}

// ---------------------------------------------------------------------------
// GRU scan v7 = v6 (weights in LDS, proven 19.5->13.5 ms) + staggered
// depth-2 polling.
//   v6 residual budget: 3960 cy/step, ~600-800 compute -> ~3100 cy in the
//   publish->observe chain. v6 samples the ring once per load RT (~700 cy):
//   discovery is quantized to a full RT. v7 keeps TWO sample-pairs in
//   flight, phase-shifted, via counted `s_waitcnt vmcnt(2)` (T4 idiom,
//   never vmcnt(0) in-loop) -> sampling period ~RT/2.
//   Compiler traps handled:
//     - sched_barrier(0) after every counted waitcnt (hipcc hoists the
//       register-only tag check past asm waitcnt otherwise — rule #18).
//     - "=&v" early-clobber on load outputs sharing an asm with inputs.
//     - loop exits with <=4 loads still in flight: regs kept live via
//       dummy-use asm and drained by vmcnt(0) AFTER the FMA+reduce phase
//       (~600 cy later -> drain is free; draining at loop-exit would eat
//       a full RT on the critical path).
//     - every-64-tries fallback via compiler-emitted SYSTEM atomic load:
//       if the asm cache flags (sc0 sc1) were ever stale-served, we
//       degrade to v6 behavior instead of livelocking.
//   Everything else byte-identical to v6 (same math order -> same absmax).
// ---------------------------------------------------------------------------
#define RING 8
#define UPB  8                 // units per block
#define NBLK (H / UPB)         // 128 blocks

#define POLL_ISSUE(x0, x1)                                              \
    asm volatile("global_load_dwordx2 %0, %2, off sc0 sc1\n\t"          \
                 "global_load_dwordx2 %1, %3, off sc0 sc1"              \
                 : "=&v"(x0), "=&v"(x1) : "v"(p0), "v"(p1) : "memory")

__global__ __launch_bounds__(512, 2) void gru_scan(
    const float* __restrict__ xu, const float* __restrict__ xr, const float* __restrict__ xc,
    const float* __restrict__ Wu, const float* __restrict__ Wr, const float* __restrict__ W,
    unsigned long long* __restrict__ th,  // RING*H tagged pairs (no init needed)
    float* __restrict__ out)              // d_out: [H h_final][SEQ*H outputs]
{
    // 96 KB weights + 8 KB hs = 104 KB LDS -> 1 block/CU
    __shared__ __align__(16) float4 wl[3 * UPB * 256];  // [mat][unit][k/4]
    __shared__ __align__(16) float hs[2][H];

    const int bid  = blockIdx.x;     // 0..127
    const int tid  = threadIdx.x;    // 0..511
    const int wid  = tid >> 6;       // 0..7
    const int lane = tid & 63;
    const int j    = bid * UPB + wid;     // hidden unit owned by this wave

    // ---- one-time: stage this block's weight rows into LDS --------------
    {
        const float4* src[3] = {
            (const float4*)(Wu + (size_t)bid * UPB * H),
            (const float4*)(Wr + (size_t)bid * UPB * H),
            (const float4*)(W  + (size_t)bid * UPB * H)};
        for (int idx = tid; idx < 3 * UPB * 256; idx += 512) {
            const int M = idx >> 11;          // /2048
            wl[idx] = src[M][idx & 2047];     // rows are contiguous per mat
        }
    }
    __syncthreads();

    float* outs = out + H;
    float hprev = 0.f;               // lane0: previous h[j]

    const float4* wu4 = &wl[(0 * UPB + wid) * 256];
    const float4* wr4 = &wl[(1 * UPB + wid) * 256];
    const float4* wc4 = &wl[(2 * UPB + wid) * 256];

    // staggered-poll sample registers (live across the FMA phase; drained
    // and reusable only after the mid-iteration vmcnt(0))
    unsigned long long a0 = 0, a1 = 0, b0 = 0, b1 = 0;

    for (int t = 0; t < SEQ; t++) {
        // prefetch x-projections (latency hides under the poll)
        float axu = 0.f, axr = 0.f, axc = 0.f;
        if (lane == 0) {
            axu = xu[(size_t)t * H + j];
            axr = xr[(size_t)t * H + j];
            axc = xc[(size_t)t * H + j];
        }

        // issue weight ds_reads early: lgkmcnt is independent of the poll's
        // vmcnt, so these complete during the MALL round trip.
        float4 wu[4], wr[4], wc[4];
#pragma unroll
        for (int m = 0; m < 4; m++) {
            wu[m] = wu4[m * 64 + lane];
            wr[m] = wr4[m * 64 + lane];
            wc[m] = wc4[m * 64 + lane];
        }

        float* hb = hs[t & 1];
        if (t == 0) {
            hb[wid * 128 + lane]      = 0.f;   // h0 = 0, nothing to poll
            hb[wid * 128 + 64 + lane] = 0.f;
        } else {
            // wave w polls units [w*128, w*128+128) of slot (t&7) for tag t,
            // with two phase-shifted sample pairs in flight.
            const unsigned long long* p0 = th + (size_t)(t & (RING - 1)) * H
                                              + wid * 128 + lane;
            const unsigned long long* p1 = p0 + 64;
            unsigned long long v0, v1;
            POLL_ISSUE(a0, a1);                 // sample pair A
            POLL_ISSUE(b0, b1);                 // sample pair B (staggered)
            int tries = 0;
            for (;;) {
                asm volatile("s_waitcnt vmcnt(2)" ::: "memory");  // A landed
                __builtin_amdgcn_sched_barrier(0);
                if (__all(((int)(a0 >> 32) == t) & ((int)(a1 >> 32) == t))) {
                    v0 = a0; v1 = a1; break;
                }
                POLL_ISSUE(a0, a1);             // re-arm A
                asm volatile("s_waitcnt vmcnt(2)" ::: "memory");  // B landed
                __builtin_amdgcn_sched_barrier(0);
                if (__all(((int)(b0 >> 32) == t) & ((int)(b1 >> 32) == t))) {
                    v0 = b0; v1 = b1; break;
                }
                POLL_ISSUE(b0, b1);             // re-arm B
                if (((++tries) & 63) == 0) {
                    // safety net: guaranteed-correct compiler-emitted system
                    // loads (cold path; prevents livelock if asm cache flags
                    // were ever wrong).
                    unsigned long long c0 = __hip_atomic_load(p0, __ATOMIC_RELAXED, __HIP_MEMORY_SCOPE_SYSTEM);
                    unsigned long long c1 = __hip_atomic_load(p1, __ATOMIC_RELAXED, __HIP_MEMORY_SCOPE_SYSTEM);
                    if (__all(((int)(c0 >> 32) == t) & ((int)(c1 >> 32) == t))) {
                        v0 = c0; v1 = c1; break;
                    }
                }
            }
            hb[wid * 128 + lane]      = __uint_as_float((unsigned)v0);
            hb[wid * 128 + 64 + lane] = __uint_as_float((unsigned)v1);
            // up to 4 poll loads still in flight into a0..b1 — drained below,
            // after the FMA phase (off the critical path).
        }
        __syncthreads();   // the ONLY barrier per step (hs double-buffered)

        const float4* hsl = (const float4*)hb;
        float au = 0.f, ar = 0.f, aw = 0.f;
#pragma unroll
        for (int m = 0; m < 4; m++) {
            float4 h = hsl[m * 64 + lane];
            au += wu[m].x * h.x + wu[m].y * h.y + wu[m].z * h.z + wu[m].w * h.w;
            ar += wr[m].x * h.x + wr[m].y * h.y + wr[m].z * h.z + wr[m].w * h.w;
            aw += wc[m].x * h.x + wc[m].y * h.y + wc[m].z * h.z + wc[m].w * h.w;
        }

#pragma unroll
        for (int off = 32; off > 0; off >>= 1) {
            au += __shfl_xor(au, off, 64);
            ar += __shfl_xor(ar, off, 64);
            aw += __shfl_xor(aw, off, 64);
        }

        // drain dangling poll samples now (~600 cy after issue -> free);
        // keeps a0..b1 regs live until the loads have landed so the
        // allocator cannot recycle them mid-flight.
        asm volatile("s_waitcnt vmcnt(0)" ::: "memory");
        __builtin_amdgcn_sched_barrier(0);
        asm volatile("" :: "v"(a0), "v"(a1), "v"(b0), "v"(b1));

        if (lane == 0) {
            float u    = 1.f / (1.f + __expf(-(axu + au)));
            float r    = 1.f / (1.f + __expf(-(axr + ar)));
            float cand = 1.f / (1.f + __expf(-(axc + r * aw)));
            float hnew = u * hprev + (1.f - u) * cand;
            hprev = hnew;
            // publish (value, tag=t+1) in ONE 8B system-scope store
            unsigned long long pkt =
                ((unsigned long long)(unsigned)(t + 1) << 32) |
                (unsigned long long)__float_as_uint(hnew);
            unsigned long long* q = th + (size_t)((t + 1) & (RING - 1)) * H + j;
            __hip_atomic_store(q, pkt, __ATOMIC_RELAXED, __HIP_MEMORY_SCOPE_SYSTEM);
            outs[(size_t)t * H + j] = hnew;       // plain cached store
            if (t == SEQ - 1) out[j] = hnew;      // h_final
        }
        // no trailing barrier: next step stages into the other hs buffer;
        // buffer reuse is gated by the NEXT step's barrier.
    }
}

// ---------------------------------------------------------------------------
extern "C" void kernel_launch(void* const* d_in, const int* in_sizes, int n_in,
                              void* d_out, int out_size, void* d_ws, size_t ws_size,
                              hipStream_t stream) {
    const float* x  = (const float*)d_in[0];
    const float* Uu = (const float*)d_in[1];
    const float* Wu = (const float*)d_in[2];
    const float* Bu = (const float*)d_in[3];
    const float* Ur = (const float*)d_in[4];
    const float* Wr = (const float*)d_in[5];
    const float* Br = (const float*)d_in[6];
    const float* U  = (const float*)d_in[7];
    const float* W  = (const float*)d_in[8];
    const float* B  = (const float*)d_in[9];

    char* ws = (char*)d_ws;
    const size_t MAT = (size_t)SEQ * H * sizeof(float);  // 32 MB
    float* xu = (float*)(ws);
    float* xr = (float*)(ws + MAT);
    float* xc = (float*)(ws + 2 * MAT);
    unsigned long long* th = (unsigned long long*)(ws + 3 * MAT);  // 64 KB ring

    dim3 g(H / 64, SEQ / 64, 3);
    proj_gemm<<<g, 256, 0, stream>>>(x, Uu, Bu, xu, Ur, Br, xr, U, B, xc);

    gru_scan<<<NBLK, 512, 0, stream>>>(xu, xr, xc, Wu, Wr, W, th, (float*)d_out);
}